// Round 11
// baseline (636.837 us; speedup 1.0000x reference)
//
#include <hip/hip_runtime.h>
#include <math.h>
#include <stdint.h>

#define HW 512
#define NACT 30
#define NINACT 34

// merged K_A role ranges
#define CONV_BLOCKS 1920          // 240 * 8
#define ZERO_BLOCKS 68            // 60 (fs2g) + 8 (fgw actives)
#define FG_BLOCKS   8704          // 8*32*34
#define KA_GRID (CONV_BLOCKS + ZERO_BLOCKS + FG_BLOCKS)   // 10692 = 2^2*3^5*11

struct Maps {
    int src_i[64];
    int src_j[64];
    int mask[64];
    int aidx[64];
    int act_k[NACT];
    int inact_k[NINACT];
};

static Maps make_maps() {
    Maps m;
    for (int k = 0; k < 64; k++) { m.src_i[k]=0; m.src_j[k]=0; m.mask[k]=0; m.aidx[k]=-1; }
    for (int i = 1; i <= 8; i++)
        for (int j = 1; j <= 8; j++) {
            int k = i*j-1;
            m.src_i[k]=i-1; m.src_j[k]=j-1; m.mask[k]=1;
        }
    int cnt=0, icnt=0;
    for (int k=0;k<64;k++) {
        if (m.mask[k]) { m.aidx[k]=cnt; if (cnt < NACT) m.act_k[cnt]=k; cnt++; }
        else           { if (icnt < NINACT) m.inact_k[icnt]=k; icnt++; }
    }
    return m;
}

// ---------------- K_A: role-dispatched {conv | zero | fg}, roles INTERLEAVED ------
// gid = (blockIdx.x * 3571) % KA_GRID is a bijection (3571 coprime to 10692), so
// the work partition is identical but dispatch order mixes VALU/LDS-bound conv
// blocks with HBM-streaming fg blocks -> both pipes busy throughout.
__global__ __launch_bounds__(256, 8) void k_A(
        const float* __restrict__ x, const float* __restrict__ w30,
        const float* __restrict__ b30, float* __restrict__ B,
        float* __restrict__ fgw, float* __restrict__ fs2g, Maps m) {
    int gid = (int)(((long long)blockIdx.x * 3571) % KA_GRID);
    int t = threadIdx.x;

    if (gid < CONV_BLOCKS) {
        // ---------------- conv role ----------------
        int blk = gid >> 3;           // b*30 + a
        int rt  = gid & 7;            // 0..7 row tile of 8
        int a = blk % NACT, b = blk / NACT;
        int k = m.act_k[a];
        int spi = m.src_i[k], spj = m.src_j[k];
        int r0 = rt*8;

        __shared__ float wlc[288];                    // [cc(4)][dydx(9)][n(8)]
        __shared__ __align__(16) float xs[4*10*72];   // [cc][row(10)][72]; interior at 4..67

        for (int idx = t; idx < 4*10*72; idx += 256) xs[idx] = 0.f;

        int col = t & 63, tl = t >> 6;
        float acc[2][8];
        #pragma unroll
        for (int rr=0; rr<2; rr++)
            #pragma unroll
            for (int n=0;n<8;n++) acc[rr][n]=0.f;

        const float* xb = x + (size_t)b*32*HW*HW;

        for (int c0 = 0; c0 < 32; c0 += 4) {
            __syncthreads();
            for (int idx = t; idx < 288; idx += 256) {
                int cc = idx / 72;
                int rem = idx - cc*72;
                wlc[idx] = w30[((rem & 7)*32 + c0 + cc)*9 + (rem >> 3)];
            }
            for (int idx = t; idx < 640; idx += 256) {
                int cc = idx / 160;
                int rem = idx - cc*160;
                int r = rem >> 4;
                int q = rem & 15;
                int pr = r0 - 1 + r;
                float4 v = make_float4(0.f,0.f,0.f,0.f);
                if (pr >= 0 && pr < 64)
                    v = *(const float4*)(xb + (size_t)(c0+cc)*HW*HW + (size_t)(spi*64+pr)*HW + spj*64 + q*4);
                *(float4*)(xs + cc*720 + r*72 + 4 + q*4) = v;
            }
            __syncthreads();
            #pragma unroll
            for (int cc = 0; cc < 4; cc++) {
                const float* xrow = xs + cc*720 + (tl*2)*72 + 3 + col;
                const float* wb = wlc + cc*72;
                #pragma unroll
                for (int dy = 0; dy < 3; dy++) {
                    float xa0 = xrow[dy*72 + 0];
                    float xa1 = xrow[dy*72 + 1];
                    float xa2 = xrow[dy*72 + 2];
                    float xb0 = xrow[dy*72 + 72];
                    float xb1 = xrow[dy*72 + 73];
                    float xb2 = xrow[dy*72 + 74];
                    #pragma unroll
                    for (int dx = 0; dx < 3; dx++) {
                        float4 wa0 = *(const float4*)(wb + (dy*3+dx)*8);
                        float4 wa1 = *(const float4*)(wb + (dy*3+dx)*8 + 4);
                        float x0 = (dx==0) ? xa0 : ((dx==1) ? xa1 : xa2);
                        float x1 = (dx==0) ? xb0 : ((dx==1) ? xb1 : xb2);
                        acc[0][0] = fmaf(x0, wa0.x, acc[0][0]);
                        acc[0][1] = fmaf(x0, wa0.y, acc[0][1]);
                        acc[0][2] = fmaf(x0, wa0.z, acc[0][2]);
                        acc[0][3] = fmaf(x0, wa0.w, acc[0][3]);
                        acc[0][4] = fmaf(x0, wa1.x, acc[0][4]);
                        acc[0][5] = fmaf(x0, wa1.y, acc[0][5]);
                        acc[0][6] = fmaf(x0, wa1.z, acc[0][6]);
                        acc[0][7] = fmaf(x0, wa1.w, acc[0][7]);
                        acc[1][0] = fmaf(x1, wa0.x, acc[1][0]);
                        acc[1][1] = fmaf(x1, wa0.y, acc[1][1]);
                        acc[1][2] = fmaf(x1, wa0.z, acc[1][2]);
                        acc[1][3] = fmaf(x1, wa0.w, acc[1][3]);
                        acc[1][4] = fmaf(x1, wa1.x, acc[1][4]);
                        acc[1][5] = fmaf(x1, wa1.y, acc[1][5]);
                        acc[1][6] = fmaf(x1, wa1.z, acc[1][6]);
                        acc[1][7] = fmaf(x1, wa1.w, acc[1][7]);
                    }
                }
            }
        }
        float* Bp = B + (size_t)(b*NACT+a)*8*4096;
        #pragma unroll
        for (int rr=0; rr<2; rr++) {
            int y = r0 + tl*2 + rr;
            #pragma unroll
            for (int n=0;n<8;n++)
                Bp[n*4096 + y*64 + col] = fmaxf(acc[rr][n] + b30[n], 0.f);
        }
    } else if (gid < CONV_BLOCKS + ZERO_BLOCKS) {
        // ---------------- zero role ----------------
        int z = gid - CONV_BLOCKS;
        if (z < 60) {
            float4* p = (float4*)(fs2g + z*1024);
            p[t] = make_float4(0.f,0.f,0.f,0.f);
        } else {
            int b = z - 60;
            for (int idx = t; idx < 960; idx += 256) {
                int a = idx >> 5, c = idx & 31;
                fgw[(b*64 + m.act_k[a])*32 + c] = 0.f;
            }
        }
    } else {
        // ---------------- fg role (inactive patches) ----------------
        int id = gid - CONV_BLOCKS - ZERO_BLOCKS;   // ((b*32 + c)*34 + q)
        int q = id % NINACT;
        int bc = id / NINACT;
        int c = bc & 31;
        int b = bc >> 5;
        int k = m.inact_k[q];
        int pi = k >> 3, pj = k & 7;
        const float* xp = x + (size_t)(b*32+c)*HW*HW;
        float s = 0.f;
        #pragma unroll
        for (int ii = 0; ii < 4; ii++) {
            int idx4 = t + 256*ii;          // float4 index within patch, 0..1023
            int y = idx4 >> 4;
            int xx = (idx4 & 15) * 4;
            float4 v = *(const float4*)(xp + (size_t)(pi*64 + y)*HW + pj*64 + xx);
            s += v.x + v.y + v.z + v.w;
        }
        for (int off = 32; off > 0; off >>= 1) s += __shfl_down(s, off);
        __shared__ float p[4];
        if ((t & 63) == 0) p[t >> 6] = s;
        __syncthreads();
        if (t == 0) {
            float tot = p[0]+p[1]+p[2]+p[3];
            fgw[(b*64 + k)*32 + c] = tot * (1.0f/4096.0f);
        }
    }
}

// ---------------- K4a: fs2 partial over 128-L chunk; (n,c) per thread -------------
__global__ __launch_bounds__(256, 8) void k_fs2a(
        const float* __restrict__ x, const float* __restrict__ B,
        float* __restrict__ fs2g, float* __restrict__ fgw, Maps m) {
    int blk = blockIdx.x;   // b*30+a
    int rt = blockIdx.y;    // 0..31 -> L chunk [rt*128, rt*128+128)
    int a = blk % NACT, b = blk / NACT;
    int k = m.act_k[a];
    int spi = m.src_i[k], spj = m.src_j[k];
    int l0 = rt*128;

    __shared__ __align__(16) float xs[32*132];   // [c][132]; 33 f4 per channel

    int t = threadIdx.x;
    const float* xb = x + (size_t)b*32*HW*HW;
    #pragma unroll
    for (int q4 = 0; q4 < 4; q4++) {
        int idx = t + 256*q4;          // 0..1023
        int c = idx >> 5, lq = idx & 31;
        int l = l0 + lq*4;
        int y = l >> 6, xx = l & 63;
        float4 v = *(const float4*)(xb + (size_t)c*HW*HW + (size_t)(spi*64+y)*HW + spj*64 + xx);
        *(float4*)(xs + c*132 + lq*4) = v;
    }
    __syncthreads();

    int n = t >> 5, c = t & 31;
    const float4* Bg4 = (const float4*)(B + (size_t)(b*NACT+a)*8*4096 + (size_t)n*4096 + l0);
    const float4* xs4 = (const float4*)(xs + c*132);
    float facc = 0.f;
    #pragma unroll 4
    for (int q = 0; q < 32; q++) {
        float4 bv = Bg4[q];
        float4 xv = xs4[q];
        facc = fmaf(bv.x, xv.x, facc);
        facc = fmaf(bv.y, xv.y, facc);
        facc = fmaf(bv.z, xv.z, facc);
        facc = fmaf(bv.w, xv.w, facc);
    }
    atomicAdd(&fs2g[(size_t)(b*NACT+a)*256 + n*32 + c], facc);

    // fg partial for this active patch (xs untouched since staging sync)
    if (t < 32) {
        const float4* xc4 = (const float4*)(xs + t*132);
        float s = 0.f;
        #pragma unroll 4
        for (int q = 0; q < 32; q++) {
            float4 v = xc4[q];
            s += v.x + v.y + v.z + v.w;
        }
        atomicAdd(&fgw[(b*64 + k)*32 + t], s * (1.0f/4096.0f));
    }
}

// ---------------- K5: head recomputes fs3->fs5 and g, then fused epilogue ---------
__global__ __launch_bounds__(256) void k_out(
        const float* __restrict__ x, const float* __restrict__ B,
        const float* __restrict__ fs2g, const float* __restrict__ fgw,
        const float* __restrict__ w11, const float* __restrict__ b11,
        const float* __restrict__ w10, const float* __restrict__ b10,
        const float* __restrict__ w12a, const float* __restrict__ b12a,
        const float* __restrict__ w12b, const float* __restrict__ b12b,
        const float* __restrict__ w12c, const float* __restrict__ b12c,
        const float* __restrict__ w31, const float* __restrict__ b31,
        const float* __restrict__ gamma, const float* __restrict__ beta,
        const float* __restrict__ mean, const float* __restrict__ var,
        float* __restrict__ out, Maps m) {
    int blk = blockIdx.x;   // b*64 + ij
    int rt = blockIdx.y;    // 0..7
    int h  = blockIdx.z;    // 0..1 o-half
    int ij = blk & 63, b = blk >> 6;
    int i = ij >> 3, j = ij & 7;
    int K = (i+1)*(j+1) - 1;
    int aK = m.aidx[K];

    __shared__ float fs2s[8*33];
    __shared__ float fs3s[8*33];
    __shared__ float fs5s[32*8];     // [c][n]
    __shared__ float gs[32];
    __shared__ float Ms[128];        // [o_local(16)][n(8)]
    __shared__ float ss2[16], sh2[16];
    int t = threadIdx.x;

    {   // fs2 load (L2-hot: 16 blocks share each (b,aK))
        int n = t >> 5, c = t & 31;
        fs2s[n*33+c] = fs2g[(size_t)(b*NACT+aK)*256 + n*32 + c];
    }
    __syncthreads();
    {   // fs3
        int o = t >> 5, c = t & 31;
        float v = b11[o];
        #pragma unroll
        for (int n=0;n<8;n++) v += w11[o*8+n]*fs2s[n*33+c];
        fs3s[o*33+c] = fmaxf(v, 0.f);
    }
    __syncthreads();
    {   // fs5: [cp][n]
        int cp = t >> 3, n = t & 7;
        float v = b10[cp];
        #pragma unroll
        for (int c=0;c<32;c++) v += w10[cp*32+c]*fs3s[n*33+c];
        fs5s[cp*8+n] = fmaxf(v, 0.f);
    }
    if (t < 32) {   // g-MLP, row K only (fgw L2-hot)
        int c = t;
        float fg[64];
        #pragma unroll
        for (int k = 0; k < 64; k++) fg[k] = fgw[(b*64+k)*32 + c];
        float g1[8], g2[8];
        #pragma unroll
        for (int o = 0; o < 8; o++) {
            float v = b12a[o];
            #pragma unroll
            for (int k2 = 0; k2 < 64; k2++) v += w12a[o*64+k2]*fg[k2];
            g1[o] = fmaxf(v, 0.f);
        }
        #pragma unroll
        for (int o = 0; o < 8; o++) {
            float v = b12b[o];
            #pragma unroll
            for (int k2 = 0; k2 < 8; k2++) v += w12b[o*8+k2]*g1[k2];
            g2[o] = fmaxf(v, 0.f);
        }
        float v = b12c[K];
        #pragma unroll
        for (int k2 = 0; k2 < 8; k2++) v += w12c[K*8+k2]*g2[k2];
        gs[c] = 1.f / (1.f + expf(-v));
    } else if (t >= 128 && t < 144) {   // BN constants (independent of LDS)
        int ol = t - 128;
        int o = h*16 + ol;
        float sc = rsqrtf(var[o] + 1e-5f) * gamma[o];
        ss2[ol] = sc;
        sh2[ol] = (b31[o] - mean[o])*sc + beta[o];   // fold conv bias + BN shift
    }
    __syncthreads();
    if (t < 128) {   // Ms[o_local][n]
        int ol = t >> 3, n = t & 7;
        int o = h*16 + ol;
        float v = 0.f;
        #pragma unroll
        for (int c=0;c<32;c++) v += w31[o*32+c]*gs[c]*fs5s[c*8+n];
        Ms[ol*8+n] = v;
    }
    __syncthreads();

    int hh = t >> 7;                 // 0/1 -> o sub-range of 8
    int gidx = t & 127;
    int r = gidx >> 4, q = gidx & 15;
    int y = rt*8 + r;
    int Y = i*64 + y;
    int X = j*64 + q*4;
    int obase = hh*8;                // o_local base for this thread
    const float* Bp = B + (size_t)(b*NACT+aK)*8*4096 + y*64 + q*4;
    const float* xb = x + ((size_t)(b*32 + h*16 + obase)*HW + Y)*HW + X;
    float* ob = out + ((size_t)(b*32 + h*16 + obase)*HW + Y)*HW + X;

    float4 Bv[8];
    #pragma unroll
    for (int n=0;n<8;n++) Bv[n] = *(const float4*)(Bp + n*4096);

    #pragma unroll 8
    for (int oo = 0; oo < 8; oo++) {
        int ol = obase + oo;
        float4 Ma = *(const float4*)(Ms + ol*8);
        float4 Mb = *(const float4*)(Ms + ol*8 + 4);
        float so = ss2[ol], ho = sh2[ol];
        float4 xv = *(const float4*)(xb + (size_t)oo*HW*HW);
        float4 yv;
        yv.x = Bv[0].x*Ma.x + Bv[1].x*Ma.y + Bv[2].x*Ma.z + Bv[3].x*Ma.w
             + Bv[4].x*Mb.x + Bv[5].x*Mb.y + Bv[6].x*Mb.z + Bv[7].x*Mb.w;
        yv.y = Bv[0].y*Ma.x + Bv[1].y*Ma.y + Bv[2].y*Ma.z + Bv[3].y*Ma.w
             + Bv[4].y*Mb.x + Bv[5].y*Mb.y + Bv[6].y*Mb.z + Bv[7].y*Mb.w;
        yv.z = Bv[0].z*Ma.x + Bv[1].z*Ma.y + Bv[2].z*Ma.z + Bv[3].z*Ma.w
             + Bv[4].z*Mb.x + Bv[5].z*Mb.y + Bv[6].z*Mb.z + Bv[7].z*Mb.w;
        yv.w = Bv[0].w*Ma.x + Bv[1].w*Ma.y + Bv[2].w*Ma.z + Bv[3].w*Ma.w
             + Bv[4].w*Mb.x + Bv[5].w*Mb.y + Bv[6].w*Mb.z + Bv[7].w*Mb.w;
        float4 res;
        res.x = fmaxf(yv.x*so + ho, 0.f) + xv.x;
        res.y = fmaxf(yv.y*so + ho, 0.f) + xv.y;
        res.z = fmaxf(yv.z*so + ho, 0.f) + xv.z;
        res.w = fmaxf(yv.w*so + ho, 0.f) + xv.w;
        *(float4*)(ob + (size_t)oo*HW*HW) = res;
    }
}

extern "C" void kernel_launch(void* const* d_in, const int* in_sizes, int n_in,
                              void* d_out, int out_size, void* d_ws, size_t ws_size,
                              hipStream_t stream) {
    const float* x    = (const float*)d_in[0];
    const float* w30  = (const float*)d_in[1];
    const float* b30  = (const float*)d_in[2];
    const float* w10  = (const float*)d_in[3];
    const float* b10  = (const float*)d_in[4];
    const float* w11  = (const float*)d_in[5];
    const float* b11  = (const float*)d_in[6];
    const float* w12a = (const float*)d_in[7];
    const float* b12a = (const float*)d_in[8];
    const float* w12b = (const float*)d_in[9];
    const float* b12b = (const float*)d_in[10];
    const float* w12c = (const float*)d_in[11];
    const float* b12c = (const float*)d_in[12];
    const float* w31  = (const float*)d_in[13];
    const float* b31  = (const float*)d_in[14];
    const float* gam  = (const float*)d_in[15];
    const float* bet  = (const float*)d_in[16];
    const float* mea  = (const float*)d_in[17];
    const float* var  = (const float*)d_in[18];
    float* out = (float*)d_out;

    float* ws   = (float*)d_ws;
    float* B    = ws;                       // 8*30*8*4096 = 7,864,320 floats
    float* fgw  = B + 7864320;              // 8*64*32     =    16,384
    float* fs2g = fgw + 16384;              // 8*30*256    =    61,440

    static Maps m = make_maps();

    k_A   <<<dim3(KA_GRID),   256, 0, stream>>>(x, w30, b30, B, fgw, fs2g, m);
    k_fs2a<<<dim3(240, 32),   256, 0, stream>>>(x, B, fs2g, fgw, m);
    k_out <<<dim3(512, 8, 2), 256, 0, stream>>>(x, B, fs2g, fgw,
                                                w11, b11, w10, b10,
                                                w12a, b12a, w12b, b12b, w12c, b12c,
                                                w31, b31, gam, bet, mea, var, out, m);
}

// Round 12
// 633.415 us; speedup vs baseline: 1.0054x; 1.0054x over previous
//
#include <hip/hip_runtime.h>
#include <math.h>
#include <stdint.h>

#define HW 512
#define NACT 30
#define NINACT 34

// merged K_A role ranges
#define CONV_BLOCKS 1920          // 240 * 8
#define ZERO_BLOCKS 68            // 60 (fs2g) + 8 (fgw actives)
#define FG_BLOCKS   8704          // 8*32*34
#define KA_GRID (CONV_BLOCKS + ZERO_BLOCKS + FG_BLOCKS)   // 10692

struct Maps {
    int src_i[64];
    int src_j[64];
    int mask[64];
    int aidx[64];
    int act_k[NACT];
    int inact_k[NINACT];
};

static Maps make_maps() {
    Maps m;
    for (int k = 0; k < 64; k++) { m.src_i[k]=0; m.src_j[k]=0; m.mask[k]=0; m.aidx[k]=-1; }
    for (int i = 1; i <= 8; i++)
        for (int j = 1; j <= 8; j++) {
            int k = i*j-1;
            m.src_i[k]=i-1; m.src_j[k]=j-1; m.mask[k]=1;
        }
    int cnt=0, icnt=0;
    for (int k=0;k<64;k++) {
        if (m.mask[k]) { m.aidx[k]=cnt; if (cnt < NACT) m.act_k[cnt]=k; cnt++; }
        else           { if (icnt < NINACT) m.inact_k[icnt]=k; icnt++; }
    }
    return m;
}

// ---------------- K_A: role-dispatched {conv | zero | fg}, GROUPED interleave -----
// 240 groups of 44 blocks: {8 conv tiles of ONE (b,a) patch, contiguous — preserves
// R10's L2 temporal locality} + {36 contiguous fg blocks}. Tail: 64 fg + 68 zero.
// Roles mix uniformly in dispatch order (conv VALU/LDS-bound overlaps fg HBM
// streaming) WITHOUT scattering intra-role neighbors (the R11 mistake).
__global__ __launch_bounds__(256, 8) void k_A(
        const float* __restrict__ x, const float* __restrict__ w30,
        const float* __restrict__ b30, float* __restrict__ B,
        float* __restrict__ fgw, float* __restrict__ fs2g, Maps m) {
    int bid = blockIdx.x;
    int gid;
    if (bid < 10560) {
        int grp = bid / 44, off = bid - grp*44;
        gid = (off < 8) ? (grp*8 + off)                                        // conv
                        : (CONV_BLOCKS + ZERO_BLOCKS + grp*36 + (off - 8));    // fg
    } else if (bid < 10624) {
        gid = CONV_BLOCKS + ZERO_BLOCKS + 8640 + (bid - 10560);                // fg tail
    } else {
        gid = CONV_BLOCKS + (bid - 10624);                                     // zero
    }
    int t = threadIdx.x;

    if (gid < CONV_BLOCKS) {
        // ---------------- conv role ----------------
        int blk = gid >> 3;           // b*30 + a
        int rt  = gid & 7;            // 0..7 row tile of 8
        int a = blk % NACT, b = blk / NACT;
        int k = m.act_k[a];
        int spi = m.src_i[k], spj = m.src_j[k];
        int r0 = rt*8;

        __shared__ float wlc[288];                    // [cc(4)][dydx(9)][n(8)]
        __shared__ __align__(16) float xs[4*10*72];   // [cc][row(10)][72]; interior at 4..67

        for (int idx = t; idx < 4*10*72; idx += 256) xs[idx] = 0.f;

        int col = t & 63, tl = t >> 6;
        float acc[2][8];
        #pragma unroll
        for (int rr=0; rr<2; rr++)
            #pragma unroll
            for (int n=0;n<8;n++) acc[rr][n]=0.f;

        const float* xb = x + (size_t)b*32*HW*HW;

        for (int c0 = 0; c0 < 32; c0 += 4) {
            __syncthreads();
            for (int idx = t; idx < 288; idx += 256) {
                int cc = idx / 72;
                int rem = idx - cc*72;
                wlc[idx] = w30[((rem & 7)*32 + c0 + cc)*9 + (rem >> 3)];
            }
            for (int idx = t; idx < 640; idx += 256) {
                int cc = idx / 160;
                int rem = idx - cc*160;
                int r = rem >> 4;
                int q = rem & 15;
                int pr = r0 - 1 + r;
                float4 v = make_float4(0.f,0.f,0.f,0.f);
                if (pr >= 0 && pr < 64)
                    v = *(const float4*)(xb + (size_t)(c0+cc)*HW*HW + (size_t)(spi*64+pr)*HW + spj*64 + q*4);
                *(float4*)(xs + cc*720 + r*72 + 4 + q*4) = v;
            }
            __syncthreads();
            #pragma unroll
            for (int cc = 0; cc < 4; cc++) {
                const float* xrow = xs + cc*720 + (tl*2)*72 + 3 + col;
                const float* wb = wlc + cc*72;
                #pragma unroll
                for (int dy = 0; dy < 3; dy++) {
                    float xa0 = xrow[dy*72 + 0];
                    float xa1 = xrow[dy*72 + 1];
                    float xa2 = xrow[dy*72 + 2];
                    float xb0 = xrow[dy*72 + 72];
                    float xb1 = xrow[dy*72 + 73];
                    float xb2 = xrow[dy*72 + 74];
                    #pragma unroll
                    for (int dx = 0; dx < 3; dx++) {
                        float4 wa0 = *(const float4*)(wb + (dy*3+dx)*8);
                        float4 wa1 = *(const float4*)(wb + (dy*3+dx)*8 + 4);
                        float x0 = (dx==0) ? xa0 : ((dx==1) ? xa1 : xa2);
                        float x1 = (dx==0) ? xb0 : ((dx==1) ? xb1 : xb2);
                        acc[0][0] = fmaf(x0, wa0.x, acc[0][0]);
                        acc[0][1] = fmaf(x0, wa0.y, acc[0][1]);
                        acc[0][2] = fmaf(x0, wa0.z, acc[0][2]);
                        acc[0][3] = fmaf(x0, wa0.w, acc[0][3]);
                        acc[0][4] = fmaf(x0, wa1.x, acc[0][4]);
                        acc[0][5] = fmaf(x0, wa1.y, acc[0][5]);
                        acc[0][6] = fmaf(x0, wa1.z, acc[0][6]);
                        acc[0][7] = fmaf(x0, wa1.w, acc[0][7]);
                        acc[1][0] = fmaf(x1, wa0.x, acc[1][0]);
                        acc[1][1] = fmaf(x1, wa0.y, acc[1][1]);
                        acc[1][2] = fmaf(x1, wa0.z, acc[1][2]);
                        acc[1][3] = fmaf(x1, wa0.w, acc[1][3]);
                        acc[1][4] = fmaf(x1, wa1.x, acc[1][4]);
                        acc[1][5] = fmaf(x1, wa1.y, acc[1][5]);
                        acc[1][6] = fmaf(x1, wa1.z, acc[1][6]);
                        acc[1][7] = fmaf(x1, wa1.w, acc[1][7]);
                    }
                }
            }
        }
        float* Bp = B + (size_t)(b*NACT+a)*8*4096;
        #pragma unroll
        for (int rr=0; rr<2; rr++) {
            int y = r0 + tl*2 + rr;
            #pragma unroll
            for (int n=0;n<8;n++)
                Bp[n*4096 + y*64 + col] = fmaxf(acc[rr][n] + b30[n], 0.f);
        }
    } else if (gid < CONV_BLOCKS + ZERO_BLOCKS) {
        // ---------------- zero role ----------------
        int z = gid - CONV_BLOCKS;
        if (z < 60) {
            float4* p = (float4*)(fs2g + z*1024);
            p[t] = make_float4(0.f,0.f,0.f,0.f);
        } else {
            int b = z - 60;
            for (int idx = t; idx < 960; idx += 256) {
                int a = idx >> 5, c = idx & 31;
                fgw[(b*64 + m.act_k[a])*32 + c] = 0.f;
            }
        }
    } else {
        // ---------------- fg role (inactive patches) ----------------
        int id = gid - CONV_BLOCKS - ZERO_BLOCKS;   // ((b*32 + c)*34 + q)
        int q = id % NINACT;
        int bc = id / NINACT;
        int c = bc & 31;
        int b = bc >> 5;
        int k = m.inact_k[q];
        int pi = k >> 3, pj = k & 7;
        const float* xp = x + (size_t)(b*32+c)*HW*HW;
        float s = 0.f;
        #pragma unroll
        for (int ii = 0; ii < 4; ii++) {
            int idx4 = t + 256*ii;          // float4 index within patch, 0..1023
            int y = idx4 >> 4;
            int xx = (idx4 & 15) * 4;
            float4 v = *(const float4*)(xp + (size_t)(pi*64 + y)*HW + pj*64 + xx);
            s += v.x + v.y + v.z + v.w;
        }
        for (int off = 32; off > 0; off >>= 1) s += __shfl_down(s, off);
        __shared__ float p[4];
        if ((t & 63) == 0) p[t >> 6] = s;
        __syncthreads();
        if (t == 0) {
            float tot = p[0]+p[1]+p[2]+p[3];
            fgw[(b*64 + k)*32 + c] = tot * (1.0f/4096.0f);
        }
    }
}

// ---------------- K4a: fs2 partial over 128-L chunk; (n,c) per thread -------------
__global__ __launch_bounds__(256, 8) void k_fs2a(
        const float* __restrict__ x, const float* __restrict__ B,
        float* __restrict__ fs2g, float* __restrict__ fgw, Maps m) {
    int blk = blockIdx.x;   // b*30+a
    int rt = blockIdx.y;    // 0..31 -> L chunk [rt*128, rt*128+128)
    int a = blk % NACT, b = blk / NACT;
    int k = m.act_k[a];
    int spi = m.src_i[k], spj = m.src_j[k];
    int l0 = rt*128;

    __shared__ __align__(16) float xs[32*132];   // [c][132]; 33 f4 per channel

    int t = threadIdx.x;
    const float* xb = x + (size_t)b*32*HW*HW;
    #pragma unroll
    for (int q4 = 0; q4 < 4; q4++) {
        int idx = t + 256*q4;          // 0..1023
        int c = idx >> 5, lq = idx & 31;
        int l = l0 + lq*4;
        int y = l >> 6, xx = l & 63;
        float4 v = *(const float4*)(xb + (size_t)c*HW*HW + (size_t)(spi*64+y)*HW + spj*64 + xx);
        *(float4*)(xs + c*132 + lq*4) = v;
    }
    __syncthreads();

    int n = t >> 5, c = t & 31;
    const float4* Bg4 = (const float4*)(B + (size_t)(b*NACT+a)*8*4096 + (size_t)n*4096 + l0);
    const float4* xs4 = (const float4*)(xs + c*132);
    float facc = 0.f;
    #pragma unroll 4
    for (int q = 0; q < 32; q++) {
        float4 bv = Bg4[q];
        float4 xv = xs4[q];
        facc = fmaf(bv.x, xv.x, facc);
        facc = fmaf(bv.y, xv.y, facc);
        facc = fmaf(bv.z, xv.z, facc);
        facc = fmaf(bv.w, xv.w, facc);
    }
    atomicAdd(&fs2g[(size_t)(b*NACT+a)*256 + n*32 + c], facc);

    // fg partial for this active patch (xs untouched since staging sync)
    if (t < 32) {
        const float4* xc4 = (const float4*)(xs + t*132);
        float s = 0.f;
        #pragma unroll 4
        for (int q = 0; q < 32; q++) {
            float4 v = xc4[q];
            s += v.x + v.y + v.z + v.w;
        }
        atomicAdd(&fgw[(b*64 + k)*32 + t], s * (1.0f/4096.0f));
    }
}

// ---------------- K5: head recomputes fs3->fs5 and g, then fused epilogue ---------
__global__ __launch_bounds__(256) void k_out(
        const float* __restrict__ x, const float* __restrict__ B,
        const float* __restrict__ fs2g, const float* __restrict__ fgw,
        const float* __restrict__ w11, const float* __restrict__ b11,
        const float* __restrict__ w10, const float* __restrict__ b10,
        const float* __restrict__ w12a, const float* __restrict__ b12a,
        const float* __restrict__ w12b, const float* __restrict__ b12b,
        const float* __restrict__ w12c, const float* __restrict__ b12c,
        const float* __restrict__ w31, const float* __restrict__ b31,
        const float* __restrict__ gamma, const float* __restrict__ beta,
        const float* __restrict__ mean, const float* __restrict__ var,
        float* __restrict__ out, Maps m) {
    int blk = blockIdx.x;   // b*64 + ij
    int rt = blockIdx.y;    // 0..7
    int h  = blockIdx.z;    // 0..1 o-half
    int ij = blk & 63, b = blk >> 6;
    int i = ij >> 3, j = ij & 7;
    int K = (i+1)*(j+1) - 1;
    int aK = m.aidx[K];

    __shared__ float fs2s[8*33];
    __shared__ float fs3s[8*33];
    __shared__ float fs5s[32*8];     // [c][n]
    __shared__ float gs[32];
    __shared__ float Ms[128];        // [o_local(16)][n(8)]
    __shared__ float ss2[16], sh2[16];
    int t = threadIdx.x;

    {   // fs2 load (L2-hot: 16 blocks share each (b,aK))
        int n = t >> 5, c = t & 31;
        fs2s[n*33+c] = fs2g[(size_t)(b*NACT+aK)*256 + n*32 + c];
    }
    __syncthreads();
    {   // fs3
        int o = t >> 5, c = t & 31;
        float v = b11[o];
        #pragma unroll
        for (int n=0;n<8;n++) v += w11[o*8+n]*fs2s[n*33+c];
        fs3s[o*33+c] = fmaxf(v, 0.f);
    }
    __syncthreads();
    {   // fs5: [cp][n]
        int cp = t >> 3, n = t & 7;
        float v = b10[cp];
        #pragma unroll
        for (int c=0;c<32;c++) v += w10[cp*32+c]*fs3s[n*33+c];
        fs5s[cp*8+n] = fmaxf(v, 0.f);
    }
    if (t < 32) {   // g-MLP, row K only (fgw L2-hot)
        int c = t;
        float fg[64];
        #pragma unroll
        for (int k = 0; k < 64; k++) fg[k] = fgw[(b*64+k)*32 + c];
        float g1[8], g2[8];
        #pragma unroll
        for (int o = 0; o < 8; o++) {
            float v = b12a[o];
            #pragma unroll
            for (int k2 = 0; k2 < 64; k2++) v += w12a[o*64+k2]*fg[k2];
            g1[o] = fmaxf(v, 0.f);
        }
        #pragma unroll
        for (int o = 0; o < 8; o++) {
            float v = b12b[o];
            #pragma unroll
            for (int k2 = 0; k2 < 8; k2++) v += w12b[o*8+k2]*g1[k2];
            g2[o] = fmaxf(v, 0.f);
        }
        float v = b12c[K];
        #pragma unroll
        for (int k2 = 0; k2 < 8; k2++) v += w12c[K*8+k2]*g2[k2];
        gs[c] = 1.f / (1.f + expf(-v));
    } else if (t >= 128 && t < 144) {   // BN constants (independent of LDS)
        int ol = t - 128;
        int o = h*16 + ol;
        float sc = rsqrtf(var[o] + 1e-5f) * gamma[o];
        ss2[ol] = sc;
        sh2[ol] = (b31[o] - mean[o])*sc + beta[o];   // fold conv bias + BN shift
    }
    __syncthreads();
    if (t < 128) {   // Ms[o_local][n]
        int ol = t >> 3, n = t & 7;
        int o = h*16 + ol;
        float v = 0.f;
        #pragma unroll
        for (int c=0;c<32;c++) v += w31[o*32+c]*gs[c]*fs5s[c*8+n];
        Ms[ol*8+n] = v;
    }
    __syncthreads();

    int hh = t >> 7;                 // 0/1 -> o sub-range of 8
    int gidx = t & 127;
    int r = gidx >> 4, q = gidx & 15;
    int y = rt*8 + r;
    int Y = i*64 + y;
    int X = j*64 + q*4;
    int obase = hh*8;                // o_local base for this thread
    const float* Bp = B + (size_t)(b*NACT+aK)*8*4096 + y*64 + q*4;
    const float* xb = x + ((size_t)(b*32 + h*16 + obase)*HW + Y)*HW + X;
    float* ob = out + ((size_t)(b*32 + h*16 + obase)*HW + Y)*HW + X;

    float4 Bv[8];
    #pragma unroll
    for (int n=0;n<8;n++) Bv[n] = *(const float4*)(Bp + n*4096);

    #pragma unroll 8
    for (int oo = 0; oo < 8; oo++) {
        int ol = obase + oo;
        float4 Ma = *(const float4*)(Ms + ol*8);
        float4 Mb = *(const float4*)(Ms + ol*8 + 4);
        float so = ss2[ol], ho = sh2[ol];
        float4 xv = *(const float4*)(xb + (size_t)oo*HW*HW);
        float4 yv;
        yv.x = Bv[0].x*Ma.x + Bv[1].x*Ma.y + Bv[2].x*Ma.z + Bv[3].x*Ma.w
             + Bv[4].x*Mb.x + Bv[5].x*Mb.y + Bv[6].x*Mb.z + Bv[7].x*Mb.w;
        yv.y = Bv[0].y*Ma.x + Bv[1].y*Ma.y + Bv[2].y*Ma.z + Bv[3].y*Ma.w
             + Bv[4].y*Mb.x + Bv[5].y*Mb.y + Bv[6].y*Mb.z + Bv[7].y*Mb.w;
        yv.z = Bv[0].z*Ma.x + Bv[1].z*Ma.y + Bv[2].z*Ma.z + Bv[3].z*Ma.w
             + Bv[4].z*Mb.x + Bv[5].z*Mb.y + Bv[6].z*Mb.z + Bv[7].z*Mb.w;
        yv.w = Bv[0].w*Ma.x + Bv[1].w*Ma.y + Bv[2].w*Ma.z + Bv[3].w*Ma.w
             + Bv[4].w*Mb.x + Bv[5].w*Mb.y + Bv[6].w*Mb.z + Bv[7].w*Mb.w;
        float4 res;
        res.x = fmaxf(yv.x*so + ho, 0.f) + xv.x;
        res.y = fmaxf(yv.y*so + ho, 0.f) + xv.y;
        res.z = fmaxf(yv.z*so + ho, 0.f) + xv.z;
        res.w = fmaxf(yv.w*so + ho, 0.f) + xv.w;
        *(float4*)(ob + (size_t)oo*HW*HW) = res;
    }
}

extern "C" void kernel_launch(void* const* d_in, const int* in_sizes, int n_in,
                              void* d_out, int out_size, void* d_ws, size_t ws_size,
                              hipStream_t stream) {
    const float* x    = (const float*)d_in[0];
    const float* w30  = (const float*)d_in[1];
    const float* b30  = (const float*)d_in[2];
    const float* w10  = (const float*)d_in[3];
    const float* b10  = (const float*)d_in[4];
    const float* w11  = (const float*)d_in[5];
    const float* b11  = (const float*)d_in[6];
    const float* w12a = (const float*)d_in[7];
    const float* b12a = (const float*)d_in[8];
    const float* w12b = (const float*)d_in[9];
    const float* b12b = (const float*)d_in[10];
    const float* w12c = (const float*)d_in[11];
    const float* b12c = (const float*)d_in[12];
    const float* w31  = (const float*)d_in[13];
    const float* b31  = (const float*)d_in[14];
    const float* gam  = (const float*)d_in[15];
    const float* bet  = (const float*)d_in[16];
    const float* mea  = (const float*)d_in[17];
    const float* var  = (const float*)d_in[18];
    float* out = (float*)d_out;

    float* ws   = (float*)d_ws;
    float* B    = ws;                       // 8*30*8*4096 = 7,864,320 floats
    float* fgw  = B + 7864320;              // 8*64*32     =    16,384
    float* fs2g = fgw + 16384;              // 8*30*256    =    61,440

    static Maps m = make_maps();

    k_A   <<<dim3(KA_GRID),   256, 0, stream>>>(x, w30, b30, B, fgw, fs2g, m);
    k_fs2a<<<dim3(240, 32),   256, 0, stream>>>(x, B, fs2g, fgw, m);
    k_out <<<dim3(512, 8, 2), 256, 0, stream>>>(x, B, fs2g, fgw,
                                                w11, b11, w10, b10,
                                                w12a, b12a, w12b, b12b, w12c, b12c,
                                                w31, b31, gam, bet, mea, var, out, m);
}

// Round 13
// 604.165 us; speedup vs baseline: 1.0541x; 1.0484x over previous
//
#include <hip/hip_runtime.h>
#include <math.h>
#include <stdint.h>

#define HW 512
#define NACT 30
#define NINACT 34

// merged K_A role ranges
#define CONV_BLOCKS 1920          // 240 * 8
#define ZERO_BLOCKS 68            // 60 (fs2g) + 8 (fgw actives)
#define FG_BLOCKS   8704          // 8*32*34
#define KA_GRID (CONV_BLOCKS + ZERO_BLOCKS + FG_BLOCKS)

struct Maps {
    int src_i[64];
    int src_j[64];
    int mask[64];
    int aidx[64];
    int act_k[NACT];
    int inact_k[NINACT];
};

static Maps make_maps() {
    Maps m;
    for (int k = 0; k < 64; k++) { m.src_i[k]=0; m.src_j[k]=0; m.mask[k]=0; m.aidx[k]=-1; }
    for (int i = 1; i <= 8; i++)
        for (int j = 1; j <= 8; j++) {
            int k = i*j-1;
            m.src_i[k]=i-1; m.src_j[k]=j-1; m.mask[k]=1;
        }
    int cnt=0, icnt=0;
    for (int k=0;k<64;k++) {
        if (m.mask[k]) { m.aidx[k]=cnt; if (cnt < NACT) m.act_k[cnt]=k; cnt++; }
        else           { if (icnt < NINACT) m.inact_k[icnt]=k; icnt++; }
    }
    return m;
}

// ---------------- K_A: role-dispatched {conv | zero | fg} -------------------------
// R10 champion: identity dispatch order. Conv blocks (VALU/LDS-bound) dispatch
// first with per-patch adjacency (L2 temporal locality); fg streaming fills the
// conv retire-tail. Deep role-mixing (R11 stride, R12 grouped) both regressed:
// fg's 126 MB stream evicts the per-XCD L2 patch reuse conv depends on.
__global__ __launch_bounds__(256, 8) void k_A(
        const float* __restrict__ x, const float* __restrict__ w30,
        const float* __restrict__ b30, float* __restrict__ B,
        float* __restrict__ fgw, float* __restrict__ fs2g, Maps m) {
    int gid = blockIdx.x;
    int t = threadIdx.x;

    if (gid < CONV_BLOCKS) {
        // ---------------- conv role ----------------
        int blk = gid >> 3;           // b*30 + a
        int rt  = gid & 7;            // 0..7 row tile of 8
        int a = blk % NACT, b = blk / NACT;
        int k = m.act_k[a];
        int spi = m.src_i[k], spj = m.src_j[k];
        int r0 = rt*8;

        __shared__ float wlc[288];                    // [cc(4)][dydx(9)][n(8)]
        __shared__ __align__(16) float xs[4*10*72];   // [cc][row(10)][72]; interior at 4..67

        for (int idx = t; idx < 4*10*72; idx += 256) xs[idx] = 0.f;

        int col = t & 63, tl = t >> 6;
        float acc[2][8];
        #pragma unroll
        for (int rr=0; rr<2; rr++)
            #pragma unroll
            for (int n=0;n<8;n++) acc[rr][n]=0.f;

        const float* xb = x + (size_t)b*32*HW*HW;

        for (int c0 = 0; c0 < 32; c0 += 4) {
            __syncthreads();
            for (int idx = t; idx < 288; idx += 256) {
                int cc = idx / 72;
                int rem = idx - cc*72;
                wlc[idx] = w30[((rem & 7)*32 + c0 + cc)*9 + (rem >> 3)];
            }
            for (int idx = t; idx < 640; idx += 256) {
                int cc = idx / 160;
                int rem = idx - cc*160;
                int r = rem >> 4;
                int q = rem & 15;
                int pr = r0 - 1 + r;
                float4 v = make_float4(0.f,0.f,0.f,0.f);
                if (pr >= 0 && pr < 64)
                    v = *(const float4*)(xb + (size_t)(c0+cc)*HW*HW + (size_t)(spi*64+pr)*HW + spj*64 + q*4);
                *(float4*)(xs + cc*720 + r*72 + 4 + q*4) = v;
            }
            __syncthreads();
            #pragma unroll
            for (int cc = 0; cc < 4; cc++) {
                const float* xrow = xs + cc*720 + (tl*2)*72 + 3 + col;
                const float* wb = wlc + cc*72;
                #pragma unroll
                for (int dy = 0; dy < 3; dy++) {
                    float xa0 = xrow[dy*72 + 0];
                    float xa1 = xrow[dy*72 + 1];
                    float xa2 = xrow[dy*72 + 2];
                    float xb0 = xrow[dy*72 + 72];
                    float xb1 = xrow[dy*72 + 73];
                    float xb2 = xrow[dy*72 + 74];
                    #pragma unroll
                    for (int dx = 0; dx < 3; dx++) {
                        float4 wa0 = *(const float4*)(wb + (dy*3+dx)*8);
                        float4 wa1 = *(const float4*)(wb + (dy*3+dx)*8 + 4);
                        float x0 = (dx==0) ? xa0 : ((dx==1) ? xa1 : xa2);
                        float x1 = (dx==0) ? xb0 : ((dx==1) ? xb1 : xb2);
                        acc[0][0] = fmaf(x0, wa0.x, acc[0][0]);
                        acc[0][1] = fmaf(x0, wa0.y, acc[0][1]);
                        acc[0][2] = fmaf(x0, wa0.z, acc[0][2]);
                        acc[0][3] = fmaf(x0, wa0.w, acc[0][3]);
                        acc[0][4] = fmaf(x0, wa1.x, acc[0][4]);
                        acc[0][5] = fmaf(x0, wa1.y, acc[0][5]);
                        acc[0][6] = fmaf(x0, wa1.z, acc[0][6]);
                        acc[0][7] = fmaf(x0, wa1.w, acc[0][7]);
                        acc[1][0] = fmaf(x1, wa0.x, acc[1][0]);
                        acc[1][1] = fmaf(x1, wa0.y, acc[1][1]);
                        acc[1][2] = fmaf(x1, wa0.z, acc[1][2]);
                        acc[1][3] = fmaf(x1, wa0.w, acc[1][3]);
                        acc[1][4] = fmaf(x1, wa1.x, acc[1][4]);
                        acc[1][5] = fmaf(x1, wa1.y, acc[1][5]);
                        acc[1][6] = fmaf(x1, wa1.z, acc[1][6]);
                        acc[1][7] = fmaf(x1, wa1.w, acc[1][7]);
                    }
                }
            }
        }
        float* Bp = B + (size_t)(b*NACT+a)*8*4096;
        #pragma unroll
        for (int rr=0; rr<2; rr++) {
            int y = r0 + tl*2 + rr;
            #pragma unroll
            for (int n=0;n<8;n++)
                Bp[n*4096 + y*64 + col] = fmaxf(acc[rr][n] + b30[n], 0.f);
        }
    } else if (gid < CONV_BLOCKS + ZERO_BLOCKS) {
        // ---------------- zero role ----------------
        int z = gid - CONV_BLOCKS;
        if (z < 60) {
            float4* p = (float4*)(fs2g + z*1024);
            p[t] = make_float4(0.f,0.f,0.f,0.f);
        } else {
            int b = z - 60;
            for (int idx = t; idx < 960; idx += 256) {
                int a = idx >> 5, c = idx & 31;
                fgw[(b*64 + m.act_k[a])*32 + c] = 0.f;
            }
        }
    } else {
        // ---------------- fg role (inactive patches) ----------------
        int id = gid - CONV_BLOCKS - ZERO_BLOCKS;   // ((b*32 + c)*34 + q)
        int q = id % NINACT;
        int bc = id / NINACT;
        int c = bc & 31;
        int b = bc >> 5;
        int k = m.inact_k[q];
        int pi = k >> 3, pj = k & 7;
        const float* xp = x + (size_t)(b*32+c)*HW*HW;
        float s = 0.f;
        #pragma unroll
        for (int ii = 0; ii < 4; ii++) {
            int idx4 = t + 256*ii;          // float4 index within patch, 0..1023
            int y = idx4 >> 4;
            int xx = (idx4 & 15) * 4;
            float4 v = *(const float4*)(xp + (size_t)(pi*64 + y)*HW + pj*64 + xx);
            s += v.x + v.y + v.z + v.w;
        }
        for (int off = 32; off > 0; off >>= 1) s += __shfl_down(s, off);
        __shared__ float p[4];
        if ((t & 63) == 0) p[t >> 6] = s;
        __syncthreads();
        if (t == 0) {
            float tot = p[0]+p[1]+p[2]+p[3];
            fgw[(b*64 + k)*32 + c] = tot * (1.0f/4096.0f);
        }
    }
}

// ---------------- K4a: fs2 partial over 128-L chunk; (n,c) per thread -------------
__global__ __launch_bounds__(256, 8) void k_fs2a(
        const float* __restrict__ x, const float* __restrict__ B,
        float* __restrict__ fs2g, float* __restrict__ fgw, Maps m) {
    int blk = blockIdx.x;   // b*30+a
    int rt = blockIdx.y;    // 0..31 -> L chunk [rt*128, rt*128+128)
    int a = blk % NACT, b = blk / NACT;
    int k = m.act_k[a];
    int spi = m.src_i[k], spj = m.src_j[k];
    int l0 = rt*128;

    __shared__ __align__(16) float xs[32*132];   // [c][132]; 33 f4 per channel

    int t = threadIdx.x;
    const float* xb = x + (size_t)b*32*HW*HW;
    #pragma unroll
    for (int q4 = 0; q4 < 4; q4++) {
        int idx = t + 256*q4;          // 0..1023
        int c = idx >> 5, lq = idx & 31;
        int l = l0 + lq*4;
        int y = l >> 6, xx = l & 63;
        float4 v = *(const float4*)(xb + (size_t)c*HW*HW + (size_t)(spi*64+y)*HW + spj*64 + xx);
        *(float4*)(xs + c*132 + lq*4) = v;
    }
    __syncthreads();

    int n = t >> 5, c = t & 31;
    const float4* Bg4 = (const float4*)(B + (size_t)(b*NACT+a)*8*4096 + (size_t)n*4096 + l0);
    const float4* xs4 = (const float4*)(xs + c*132);
    float facc = 0.f;
    #pragma unroll 4
    for (int q = 0; q < 32; q++) {
        float4 bv = Bg4[q];
        float4 xv = xs4[q];
        facc = fmaf(bv.x, xv.x, facc);
        facc = fmaf(bv.y, xv.y, facc);
        facc = fmaf(bv.z, xv.z, facc);
        facc = fmaf(bv.w, xv.w, facc);
    }
    atomicAdd(&fs2g[(size_t)(b*NACT+a)*256 + n*32 + c], facc);

    // fg partial for this active patch (xs untouched since staging sync)
    if (t < 32) {
        const float4* xc4 = (const float4*)(xs + t*132);
        float s = 0.f;
        #pragma unroll 4
        for (int q = 0; q < 32; q++) {
            float4 v = xc4[q];
            s += v.x + v.y + v.z + v.w;
        }
        atomicAdd(&fgw[(b*64 + k)*32 + t], s * (1.0f/4096.0f));
    }
}

// ---------------- K5: head recomputes fs3->fs5 and g, then fused epilogue ---------
__global__ __launch_bounds__(256) void k_out(
        const float* __restrict__ x, const float* __restrict__ B,
        const float* __restrict__ fs2g, const float* __restrict__ fgw,
        const float* __restrict__ w11, const float* __restrict__ b11,
        const float* __restrict__ w10, const float* __restrict__ b10,
        const float* __restrict__ w12a, const float* __restrict__ b12a,
        const float* __restrict__ w12b, const float* __restrict__ b12b,
        const float* __restrict__ w12c, const float* __restrict__ b12c,
        const float* __restrict__ w31, const float* __restrict__ b31,
        const float* __restrict__ gamma, const float* __restrict__ beta,
        const float* __restrict__ mean, const float* __restrict__ var,
        float* __restrict__ out, Maps m) {
    int blk = blockIdx.x;   // b*64 + ij
    int rt = blockIdx.y;    // 0..7
    int h  = blockIdx.z;    // 0..1 o-half
    int ij = blk & 63, b = blk >> 6;
    int i = ij >> 3, j = ij & 7;
    int K = (i+1)*(j+1) - 1;
    int aK = m.aidx[K];

    __shared__ float fs2s[8*33];
    __shared__ float fs3s[8*33];
    __shared__ float fs5s[32*8];     // [c][n]
    __shared__ float gs[32];
    __shared__ float Ms[128];        // [o_local(16)][n(8)]
    __shared__ float ss2[16], sh2[16];
    int t = threadIdx.x;

    {   // fs2 load (L2-hot: 16 blocks share each (b,aK))
        int n = t >> 5, c = t & 31;
        fs2s[n*33+c] = fs2g[(size_t)(b*NACT+aK)*256 + n*32 + c];
    }
    __syncthreads();
    {   // fs3
        int o = t >> 5, c = t & 31;
        float v = b11[o];
        #pragma unroll
        for (int n=0;n<8;n++) v += w11[o*8+n]*fs2s[n*33+c];
        fs3s[o*33+c] = fmaxf(v, 0.f);
    }
    __syncthreads();
    {   // fs5: [cp][n]
        int cp = t >> 3, n = t & 7;
        float v = b10[cp];
        #pragma unroll
        for (int c=0;c<32;c++) v += w10[cp*32+c]*fs3s[n*33+c];
        fs5s[cp*8+n] = fmaxf(v, 0.f);
    }
    if (t < 32) {   // g-MLP, row K only (fgw L2-hot)
        int c = t;
        float fg[64];
        #pragma unroll
        for (int k = 0; k < 64; k++) fg[k] = fgw[(b*64+k)*32 + c];
        float g1[8], g2[8];
        #pragma unroll
        for (int o = 0; o < 8; o++) {
            float v = b12a[o];
            #pragma unroll
            for (int k2 = 0; k2 < 64; k2++) v += w12a[o*64+k2]*fg[k2];
            g1[o] = fmaxf(v, 0.f);
        }
        #pragma unroll
        for (int o = 0; o < 8; o++) {
            float v = b12b[o];
            #pragma unroll
            for (int k2 = 0; k2 < 8; k2++) v += w12b[o*8+k2]*g1[k2];
            g2[o] = fmaxf(v, 0.f);
        }
        float v = b12c[K];
        #pragma unroll
        for (int k2 = 0; k2 < 8; k2++) v += w12c[K*8+k2]*g2[k2];
        gs[c] = 1.f / (1.f + expf(-v));
    } else if (t >= 128 && t < 144) {   // BN constants (independent of LDS)
        int ol = t - 128;
        int o = h*16 + ol;
        float sc = rsqrtf(var[o] + 1e-5f) * gamma[o];
        ss2[ol] = sc;
        sh2[ol] = (b31[o] - mean[o])*sc + beta[o];   // fold conv bias + BN shift
    }
    __syncthreads();
    if (t < 128) {   // Ms[o_local][n]
        int ol = t >> 3, n = t & 7;
        int o = h*16 + ol;
        float v = 0.f;
        #pragma unroll
        for (int c=0;c<32;c++) v += w31[o*32+c]*gs[c]*fs5s[c*8+n];
        Ms[ol*8+n] = v;
    }
    __syncthreads();

    int hh = t >> 7;                 // 0/1 -> o sub-range of 8
    int gidx = t & 127;
    int r = gidx >> 4, q = gidx & 15;
    int y = rt*8 + r;
    int Y = i*64 + y;
    int X = j*64 + q*4;
    int obase = hh*8;                // o_local base for this thread
    const float* Bp = B + (size_t)(b*NACT+aK)*8*4096 + y*64 + q*4;
    const float* xb = x + ((size_t)(b*32 + h*16 + obase)*HW + Y)*HW + X;
    float* ob = out + ((size_t)(b*32 + h*16 + obase)*HW + Y)*HW + X;

    float4 Bv[8];
    #pragma unroll
    for (int n=0;n<8;n++) Bv[n] = *(const float4*)(Bp + n*4096);

    #pragma unroll 8
    for (int oo = 0; oo < 8; oo++) {
        int ol = obase + oo;
        float4 Ma = *(const float4*)(Ms + ol*8);
        float4 Mb = *(const float4*)(Ms + ol*8 + 4);
        float so = ss2[ol], ho = sh2[ol];
        float4 xv = *(const float4*)(xb + (size_t)oo*HW*HW);
        float4 yv;
        yv.x = Bv[0].x*Ma.x + Bv[1].x*Ma.y + Bv[2].x*Ma.z + Bv[3].x*Ma.w
             + Bv[4].x*Mb.x + Bv[5].x*Mb.y + Bv[6].x*Mb.z + Bv[7].x*Mb.w;
        yv.y = Bv[0].y*Ma.x + Bv[1].y*Ma.y + Bv[2].y*Ma.z + Bv[3].y*Ma.w
             + Bv[4].y*Mb.x + Bv[5].y*Mb.y + Bv[6].y*Mb.z + Bv[7].y*Mb.w;
        yv.z = Bv[0].z*Ma.x + Bv[1].z*Ma.y + Bv[2].z*Ma.z + Bv[3].z*Ma.w
             + Bv[4].z*Mb.x + Bv[5].z*Mb.y + Bv[6].z*Mb.z + Bv[7].z*Mb.w;
        yv.w = Bv[0].w*Ma.x + Bv[1].w*Ma.y + Bv[2].w*Ma.z + Bv[3].w*Ma.w
             + Bv[4].w*Mb.x + Bv[5].w*Mb.y + Bv[6].w*Mb.z + Bv[7].w*Mb.w;
        float4 res;
        res.x = fmaxf(yv.x*so + ho, 0.f) + xv.x;
        res.y = fmaxf(yv.y*so + ho, 0.f) + xv.y;
        res.z = fmaxf(yv.z*so + ho, 0.f) + xv.z;
        res.w = fmaxf(yv.w*so + ho, 0.f) + xv.w;
        *(float4*)(ob + (size_t)oo*HW*HW) = res;
    }
}

extern "C" void kernel_launch(void* const* d_in, const int* in_sizes, int n_in,
                              void* d_out, int out_size, void* d_ws, size_t ws_size,
                              hipStream_t stream) {
    const float* x    = (const float*)d_in[0];
    const float* w30  = (const float*)d_in[1];
    const float* b30  = (const float*)d_in[2];
    const float* w10  = (const float*)d_in[3];
    const float* b10  = (const float*)d_in[4];
    const float* w11  = (const float*)d_in[5];
    const float* b11  = (const float*)d_in[6];
    const float* w12a = (const float*)d_in[7];
    const float* b12a = (const float*)d_in[8];
    const float* w12b = (const float*)d_in[9];
    const float* b12b = (const float*)d_in[10];
    const float* w12c = (const float*)d_in[11];
    const float* b12c = (const float*)d_in[12];
    const float* w31  = (const float*)d_in[13];
    const float* b31  = (const float*)d_in[14];
    const float* gam  = (const float*)d_in[15];
    const float* bet  = (const float*)d_in[16];
    const float* mea  = (const float*)d_in[17];
    const float* var  = (const float*)d_in[18];
    float* out = (float*)d_out;

    float* ws   = (float*)d_ws;
    float* B    = ws;                       // 8*30*8*4096 = 7,864,320 floats
    float* fgw  = B + 7864320;              // 8*64*32     =    16,384
    float* fs2g = fgw + 16384;              // 8*30*256    =    61,440

    static Maps m = make_maps();

    k_A   <<<dim3(KA_GRID),   256, 0, stream>>>(x, w30, b30, B, fgw, fs2g, m);
    k_fs2a<<<dim3(240, 32),   256, 0, stream>>>(x, B, fs2g, fgw, m);
    k_out <<<dim3(512, 8, 2), 256, 0, stream>>>(x, B, fs2g, fgw,
                                                w11, b11, w10, b10,
                                                w12a, b12a, w12b, b12b, w12c, b12c,
                                                w31, b31, gam, bet, mea, var, out, m);
}